// Round 3
// baseline (641.313 us; speedup 1.0000x reference)
//
#include <hip/hip_runtime.h>
#include <stdint.h>

typedef __attribute__((ext_vector_type(8))) short short8;
typedef __attribute__((ext_vector_type(4))) float f32x4;

__device__ __forceinline__ uint32_t pk2bf(float a, float b) {
  uint32_t ua = __builtin_bit_cast(uint32_t, a);
  uint32_t ub = __builtin_bit_cast(uint32_t, b);
  ua = (ua + 0x7FFFu + ((ua >> 16) & 1u)) >> 16;
  ub = (ub + 0x7FFFu + ((ub >> 16) & 1u)) >> 16;
  return (ua & 0xFFFFu) | (ub << 16);
}
__device__ __forceinline__ uint16_t f2bf(float a) {
  uint32_t ua = __builtin_bit_cast(uint32_t, a);
  return (uint16_t)((ua + 0x7FFFu + ((ua >> 16) & 1u)) >> 16);
}
__device__ __forceinline__ float bflo(uint32_t w) { return __builtin_bit_cast(float, w << 16); }
__device__ __forceinline__ float bfhi(uint32_t w) { return __builtin_bit_cast(float, w & 0xFFFF0000u); }

// ---------------------------------------------------------------------------
// K1: QKV projection. One block = 128 rows x 512 cols of one projection.
// 512 thr = 8 waves (2 row x 4 col), wave tile 64x128, acc[4][8] f32x4.
// A,B reg-staged f32->bf16 into XOR-swizzled LDS (conflict-free ds_read_b128).
// grid = 512 rt x 3 proj (proj fastest) + XCD-chunked swizzle.
// Epilogue: bias, bf16 store, ||Q||^2/||K||^2, ks_sum.
// ---------------------------------------------------------------------------
__global__ __launch_bounds__(512, 2) void k_gemm_qkv(
    const float* __restrict__ qin, const float* __restrict__ sin_,
    const float* __restrict__ Wq, const float* __restrict__ bq,
    const float* __restrict__ Wk, const float* __restrict__ bk,
    const float* __restrict__ Wv, const float* __restrict__ bv,
    uint16_t* __restrict__ Qb, uint16_t* __restrict__ Kb, uint16_t* __restrict__ Vb,
    float* __restrict__ norms, float* __restrict__ ks_sum) {
  __shared__ uint16_t As[128 * 64];   // 16KB, swizzled
  __shared__ uint16_t Bs[512 * 64];   // 64KB, swizzled
  __shared__ float ksp[512];
  __shared__ float red[8];

  const int b0 = blockIdx.x;
  const int blk = (b0 & 7) * 192 + (b0 >> 3);  // XCD-chunked (1536 = 8*192)
  const int proj = blk % 3;                    // 0=Q 1=K 2=V (K,V adjacent -> sin reuse)
  const int rt = blk / 3;
  const int row0 = rt * 128;

  const float* A = (proj == 0) ? qin : sin_;
  const float* W = (proj == 0) ? Wq : (proj == 1) ? Wk : Wv;
  const float* Bi = (proj == 0) ? bq : (proj == 1) ? bk : bv;
  uint16_t* O = (proj == 0) ? Qb : (proj == 1) ? Kb : Vb;

  const int tid = threadIdx.x;
  const int lane = tid & 63;
  const int wv = tid >> 6;
  const int wr = wv >> 2;   // 0..1
  const int wc = wv & 3;    // 0..3
  const int l15 = lane & 15, lhi = lane >> 4;

  f32x4 acc[4][8];
#pragma unroll
  for (int m = 0; m < 4; ++m)
#pragma unroll
    for (int n = 0; n < 8; ++n) acc[m][n] = (f32x4){0.f, 0.f, 0.f, 0.f};

  for (int kt = 0; kt < 8; ++kt) {
    const int k0 = kt * 64;
    // A tile 128x64: 2048 float4, 4 iters/thread
#pragma unroll
    for (int j = 0; j < 4; ++j) {
      const int idx = j * 512 + tid;
      const int r = idx >> 4, p = idx & 15;
      const float4 v = *(const float4*)(A + (size_t)(row0 + r) * 512 + k0 + p * 4);
      uint2 pk;
      pk.x = pk2bf(v.x, v.y);
      pk.y = pk2bf(v.z, v.w);
      const int bo = (r * 128 + p * 8) ^ ((r & 7) << 4);
      *(uint2*)((char*)As + bo) = pk;
    }
    // B tile 512x64 (W rows = output cols): 8192 float4, 16 iters/thread (L2-hot)
#pragma unroll
    for (int j = 0; j < 16; ++j) {
      const int idx = j * 512 + tid;
      const int c = idx >> 4, p = idx & 15;
      const float4 v = *(const float4*)(W + (size_t)c * 512 + k0 + p * 4);
      uint2 pk;
      pk.x = pk2bf(v.x, v.y);
      pk.y = pk2bf(v.z, v.w);
      const int bo = (c * 128 + p * 8) ^ ((c & 7) << 4);
      *(uint2*)((char*)Bs + bo) = pk;
    }
    __syncthreads();
#pragma unroll
    for (int kk = 0; kk < 2; ++kk) {
      short8 af[4], bf[8];
#pragma unroll
      for (int m = 0; m < 4; ++m) {
        const int r = wr * 64 + m * 16 + l15;
        const int bo = (r * 128 + kk * 64 + lhi * 16) ^ ((r & 7) << 4);
        af[m] = *(const short8*)((char*)As + bo);
      }
#pragma unroll
      for (int n = 0; n < 8; ++n) {
        const int c = wc * 128 + n * 16 + l15;
        const int bo = (c * 128 + kk * 64 + lhi * 16) ^ ((c & 7) << 4);
        bf[n] = *(const short8*)((char*)Bs + bo);
      }
#pragma unroll
      for (int m = 0; m < 4; ++m)
#pragma unroll
        for (int n = 0; n < 8; ++n)
          acc[m][n] = __builtin_amdgcn_mfma_f32_16x16x32_bf16(af[m], bf[n], acc[m][n], 0, 0, 0);
    }
    __syncthreads();
  }

  // Epilogue
  float nrm = 0.f;
  float cs[8];
#pragma unroll
  for (int n = 0; n < 8; ++n) cs[n] = 0.f;
#pragma unroll
  for (int n = 0; n < 8; ++n) {
    const int colg = wc * 128 + n * 16 + l15;
    const float bias = Bi[colg];
#pragma unroll
    for (int m = 0; m < 4; ++m) {
      const int rowb = row0 + wr * 64 + m * 16 + lhi * 4;
#pragma unroll
      for (int r = 0; r < 4; ++r) {
        const float v = acc[m][n][r] + bias;
        O[(size_t)(rowb + r) * 512 + colg] = f2bf(v);
        nrm += v * v;
        cs[n] += v;
      }
    }
  }
#pragma unroll
  for (int o = 32; o >= 1; o >>= 1) nrm += __shfl_xor(nrm, o, 64);
  ksp[tid] = 0.f;
  if (lane == 0) red[wv] = nrm;
  __syncthreads();
  if (proj == 1) {
#pragma unroll
    for (int n = 0; n < 8; ++n) {
      cs[n] += __shfl_xor(cs[n], 16, 64);
      cs[n] += __shfl_xor(cs[n], 32, 64);
    }
    if (lhi == 0) {
#pragma unroll
      for (int n = 0; n < 8; ++n) atomicAdd(&ksp[wc * 128 + n * 16 + l15], cs[n]);
    }
  }
  __syncthreads();
  if (tid == 0 && proj < 2)
    atomicAdd(&norms[proj],
              red[0] + red[1] + red[2] + red[3] + red[4] + red[5] + red[6] + red[7]);
  if (proj == 1) atomicAdd(&ks_sum[tid], ksp[tid]);
}

// ---------------------------------------------------------------------------
// K2: kvs[h][m][d] = sum_n K[n][h*64+m] * V[n][h*64+d]. 2 heads per block.
// grid = 4 head-pairs x 64 chunks (1024 rows each). 256 thr, 4x4 per head.
// ---------------------------------------------------------------------------
__global__ __launch_bounds__(256) void k_kvs(const uint16_t* __restrict__ Kb,
                                             const uint16_t* __restrict__ Vb,
                                             float* __restrict__ kvs) {
  __shared__ uint16_t Ks[64 * 128];
  __shared__ uint16_t Vs[64 * 128];
  const int tid = threadIdx.x;
  const int hp = blockIdx.x & 3;
  const int chunk = blockIdx.x >> 2;
  const int tm = tid >> 4, td = tid & 15;
  float acc0[4][4], acc1[4][4];
#pragma unroll
  for (int a = 0; a < 4; ++a)
#pragma unroll
    for (int b = 0; b < 4; ++b) { acc0[a][b] = 0.f; acc1[a][b] = 0.f; }

  for (int nb = 0; nb < 16; ++nb) {
    const int n0 = chunk * 1024 + nb * 64;
#pragma unroll
    for (int i = 0; i < 4; ++i) {
      const int id = i * 256 + tid;
      const int row = id >> 4, c8 = id & 15;
      *(uint4*)(&Ks[row * 128 + c8 * 8]) =
          *(const uint4*)(Kb + (size_t)(n0 + row) * 512 + hp * 128 + c8 * 8);
      *(uint4*)(&Vs[row * 128 + c8 * 8]) =
          *(const uint4*)(Vb + (size_t)(n0 + row) * 512 + hp * 128 + c8 * 8);
    }
    __syncthreads();
    for (int nn = 0; nn < 64; ++nn) {
      const uint2 kw0 = *(const uint2*)(&Ks[nn * 128 + tm * 4]);
      const uint2 kw1 = *(const uint2*)(&Ks[nn * 128 + 64 + tm * 4]);
      const uint2 vw0 = *(const uint2*)(&Vs[nn * 128 + td * 4]);
      const uint2 vw1 = *(const uint2*)(&Vs[nn * 128 + 64 + td * 4]);
      const float km0[4] = {bflo(kw0.x), bfhi(kw0.x), bflo(kw0.y), bfhi(kw0.y)};
      const float km1[4] = {bflo(kw1.x), bfhi(kw1.x), bflo(kw1.y), bfhi(kw1.y)};
      const float vd0[4] = {bflo(vw0.x), bfhi(vw0.x), bflo(vw0.y), bfhi(vw0.y)};
      const float vd1[4] = {bflo(vw1.x), bfhi(vw1.x), bflo(vw1.y), bfhi(vw1.y)};
#pragma unroll
      for (int a = 0; a < 4; ++a)
#pragma unroll
        for (int b = 0; b < 4; ++b) {
          acc0[a][b] = fmaf(km0[a], vd0[b], acc0[a][b]);
          acc1[a][b] = fmaf(km1[a], vd1[b], acc1[a][b]);
        }
    }
    __syncthreads();
  }
  const int h0 = hp * 2;
#pragma unroll
  for (int a = 0; a < 4; ++a)
#pragma unroll
    for (int b = 0; b < 4; ++b) {
      atomicAdd(&kvs[(size_t)(h0 * 64 + tm * 4 + a) * 64 + td * 4 + b], acc0[a][b]);
      atomicAdd(&kvs[(size_t)((h0 + 1) * 64 + tm * 4 + a) * 64 + td * 4 + b], acc1[a][b]);
    }
}

// ---------------------------------------------------------------------------
// K2b: kvsT[d][k] = bf16(kvs[k][d])   (k = h*64+m, 512; d = 64). Tiny.
// ---------------------------------------------------------------------------
__global__ void k_kvsT(const float* __restrict__ kvs, uint16_t* __restrict__ kvsT) {
  const int t = blockIdx.x * 256 + threadIdx.x;
  const int e0 = t * 4;
  const float4 v = *(const float4*)(kvs + e0);
  const int k = e0 >> 6, d0 = e0 & 63;
  kvsT[(size_t)(d0 + 0) * 512 + k] = f2bf(v.x);
  kvsT[(size_t)(d0 + 1) * 512 + k] = f2bf(v.y);
  kvsT[(size_t)(d0 + 2) * 512 + k] = f2bf(v.z);
  kvsT[(size_t)(d0 + 3) * 512 + k] = f2bf(v.w);
}

// ---------------------------------------------------------------------------
// K3a: per (node,head): den = scale*(q_h . ks_sum_h) + N
//      a = scale/(8*den)  (folded into Q for the num GEMM)
//      b = (N/8)/den      (V-term weight)
// ---------------------------------------------------------------------------
__global__ __launch_bounds__(256) void k_den(const uint16_t* __restrict__ Qb,
                                             const float* __restrict__ ks_sum,
                                             const float* __restrict__ norms,
                                             float* __restrict__ a_buf,
                                             float* __restrict__ b_buf) {
  __shared__ float kss[512];
  const int tid = threadIdx.x;
  kss[tid] = ks_sum[tid];
  kss[tid + 256] = ks_sum[tid + 256];
  __syncthreads();
  const float scale = 1.0f / (sqrtf(norms[0]) * sqrtf(norms[1]));
  const int gid = blockIdx.x * 256 + tid;
  const int h = gid & 7, n = gid >> 3;
  const uint16_t* q = Qb + (size_t)n * 512 + h * 64;
  const float* ks = &kss[h * 64];
  float dot = 0.f;
#pragma unroll
  for (int i = 0; i < 8; ++i) {
    const uint4 w = *(const uint4*)(q + i * 8);
    const uint32_t dw[4] = {w.x, w.y, w.z, w.w};
#pragma unroll
    for (int c = 0; c < 4; ++c) {
      dot = fmaf(bflo(dw[c]), ks[i * 8 + c * 2], dot);
      dot = fmaf(bfhi(dw[c]), ks[i * 8 + c * 2 + 1], dot);
    }
  }
  const float den = fmaf(scale, dot, 65536.0f);
  a_buf[gid] = scale / (8.0f * den);
  b_buf[gid] = 8192.0f / den;
}

// ---------------------------------------------------------------------------
// K3b: term1: out[n][d] = sum_k (a[n][h(k)]*Q[n][k]) * kvsT[d][k]
// Single GEMM [65536x512]@[512x64]; head-scale folded into A staging.
// Block 128 rows, 4 waves (32 rows x 64 cols each), kvsT staged once (swizzled).
// ---------------------------------------------------------------------------
__global__ __launch_bounds__(256) void k_qkv_num(const uint16_t* __restrict__ Qb,
                                                 const uint16_t* __restrict__ kvsT,
                                                 const float* __restrict__ a_buf,
                                                 float* __restrict__ outb) {
  __shared__ uint16_t Bs[64 * 512];  // 64KB swizzled
  __shared__ uint16_t As[128 * 64];  // 16KB swizzled
  __shared__ float aS[128 * 8];
  const int tid = threadIdx.x;
  const int lane = tid & 63;
  const int wv = tid >> 6;
  const int l15 = lane & 15, lhi = lane >> 4;
  const int row0 = blockIdx.x * 128;

#pragma unroll
  for (int i = 0; i < 16; ++i) {
    const int idx = i * 256 + tid;
    const int d = idx >> 6, p = idx & 63;
    const uint4 v = *(const uint4*)(kvsT + (size_t)d * 512 + p * 8);
    const int bo = (d * 1024 + p * 16) ^ ((d & 7) << 4);
    *(uint4*)((char*)Bs + bo) = v;
  }
#pragma unroll
  for (int i = 0; i < 4; ++i) aS[i * 256 + tid] = a_buf[(size_t)row0 * 8 + i * 256 + tid];
  __syncthreads();

  f32x4 acc[2][4];
#pragma unroll
  for (int m = 0; m < 2; ++m)
#pragma unroll
    for (int n = 0; n < 4; ++n) acc[m][n] = (f32x4){0.f, 0.f, 0.f, 0.f};

  for (int kt = 0; kt < 8; ++kt) {
#pragma unroll
    for (int j = 0; j < 4; ++j) {
      const int idx = j * 256 + tid;
      const int r = idx >> 3, p = idx & 7;
      const uint4 w = *(const uint4*)(Qb + (size_t)(row0 + r) * 512 + kt * 64 + p * 8);
      const float av = aS[r * 8 + kt];
      const uint32_t dw[4] = {w.x, w.y, w.z, w.w};
      uint4 o;
      uint32_t* op = (uint32_t*)&o;
#pragma unroll
      for (int c = 0; c < 4; ++c) op[c] = pk2bf(bflo(dw[c]) * av, bfhi(dw[c]) * av);
      const int bo = (r * 128 + p * 16) ^ ((r & 7) << 4);
      *(uint4*)((char*)As + bo) = o;
    }
    __syncthreads();
#pragma unroll
    for (int kk = 0; kk < 2; ++kk) {
      short8 af[2], bfr[4];
#pragma unroll
      for (int m = 0; m < 2; ++m) {
        const int r = wv * 32 + m * 16 + l15;
        const int bo = (r * 128 + kk * 64 + lhi * 16) ^ ((r & 7) << 4);
        af[m] = *(const short8*)((char*)As + bo);
      }
#pragma unroll
      for (int n = 0; n < 4; ++n) {
        const int d = n * 16 + l15;
        const int bo = (d * 1024 + (kt * 64 + kk * 32 + lhi * 8) * 2) ^ ((d & 7) << 4);
        bfr[n] = *(const short8*)((char*)Bs + bo);
      }
#pragma unroll
      for (int m = 0; m < 2; ++m)
#pragma unroll
        for (int n = 0; n < 4; ++n)
          acc[m][n] = __builtin_amdgcn_mfma_f32_16x16x32_bf16(af[m], bfr[n], acc[m][n], 0, 0, 0);
    }
    __syncthreads();
  }
#pragma unroll
  for (int m = 0; m < 2; ++m)
#pragma unroll
    for (int n = 0; n < 4; ++n)
#pragma unroll
      for (int r = 0; r < 4; ++r) {
        const int row = row0 + wv * 32 + m * 16 + lhi * 4 + r;
        const int d = n * 16 + l15;
        outb[(size_t)row * 64 + d] = acc[m][n][r];
      }
}

// ---------------------------------------------------------------------------
// K3c: out[n][d] += sum_h b[n][h] * V[n][h*64+d]
// ---------------------------------------------------------------------------
__global__ __launch_bounds__(256) void k_vterm(const uint16_t* __restrict__ Vb,
                                               const float* __restrict__ b_buf,
                                               float* __restrict__ outb) {
  const int n = blockIdx.x * 256 + threadIdx.x;
  float bh[8];
#pragma unroll
  for (int h = 0; h < 8; ++h) bh[h] = b_buf[(size_t)n * 8 + h];
  float o[64];
#pragma unroll
  for (int i = 0; i < 16; ++i) {
    const float4 t = *(const float4*)(outb + (size_t)n * 64 + i * 4);
    o[i * 4] = t.x; o[i * 4 + 1] = t.y; o[i * 4 + 2] = t.z; o[i * 4 + 3] = t.w;
  }
#pragma unroll
  for (int h = 0; h < 8; ++h) {
    const uint16_t* vp = Vb + (size_t)n * 512 + h * 64;
    const float b = bh[h];
#pragma unroll
    for (int i = 0; i < 8; ++i) {
      const uint4 w = *(const uint4*)(vp + i * 8);
      const uint32_t dw[4] = {w.x, w.y, w.z, w.w};
#pragma unroll
      for (int c = 0; c < 4; ++c) {
        const int d = i * 8 + c * 2;
        o[d] = fmaf(b, bflo(dw[c]), o[d]);
        o[d + 1] = fmaf(b, bfhi(dw[c]), o[d + 1]);
      }
    }
  }
#pragma unroll
  for (int i = 0; i < 16; ++i) {
    float4 t;
    t.x = o[i * 4]; t.y = o[i * 4 + 1]; t.z = o[i * 4 + 2]; t.w = o[i * 4 + 3];
    *(float4*)(outb + (size_t)n * 64 + i * 4) = t;
  }
}

// ---------------------------------------------------------------------------
extern "C" void kernel_launch(void* const* d_in, const int* in_sizes, int n_in,
                              void* d_out, int out_size, void* d_ws, size_t ws_size,
                              hipStream_t stream) {
  const float* qin = (const float*)d_in[0];
  const float* sin_ = (const float*)d_in[1];
  const float* Wq = (const float*)d_in[2];
  const float* bq = (const float*)d_in[3];
  const float* Wk = (const float*)d_in[4];
  const float* bk = (const float*)d_in[5];
  const float* Wv = (const float*)d_in[6];
  const float* bv = (const float*)d_in[7];
  float* out = (float*)d_out;

  char* ws = (char*)d_ws;
  float* kvs = (float*)ws;                                   // 128KB
  float* ks_sum = (float*)(ws + 131072);                     // 2KB
  float* norms = (float*)(ws + 133120);                      // 8B
  uint16_t* kvsT = (uint16_t*)(ws + 262144);                 // 64KB
  uint16_t* Qb = (uint16_t*)(ws + (1 << 20));                // 64MB
  uint16_t* Kb = (uint16_t*)(ws + (1 << 20) + 67108864ull);  // 64MB
  uint16_t* Vb = (uint16_t*)(ws + (1 << 20) + 134217728ull); // 64MB
  // a/b overlay the Kb region (Kb is dead after k_kvs).
  float* a_buf = (float*)(ws + (1 << 20) + 67108864ull);           // 2MB
  float* b_buf = (float*)(ws + (1 << 20) + 67108864ull + 2097152); // 2MB

  hipMemsetAsync(d_ws, 0, 133128, stream);  // kvs, ks_sum, norms

  k_gemm_qkv<<<dim3(1536), dim3(512), 0, stream>>>(qin, sin_, Wq, bq, Wk, bk, Wv, bv,
                                                   Qb, Kb, Vb, norms, ks_sum);
  k_kvs<<<dim3(256), dim3(256), 0, stream>>>(Kb, Vb, kvs);
  k_kvsT<<<dim3(32), dim3(256), 0, stream>>>(kvs, kvsT);
  k_den<<<dim3(2048), dim3(256), 0, stream>>>(Qb, ks_sum, norms, a_buf, b_buf);
  k_qkv_num<<<dim3(512), dim3(256), 0, stream>>>(Qb, kvsT, a_buf, out);
  k_vterm<<<dim3(256), dim3(256), 0, stream>>>(Vb, b_buf, out);
}

// Round 4
// 454.728 us; speedup vs baseline: 1.4103x; 1.4103x over previous
//
#include <hip/hip_runtime.h>
#include <stdint.h>

typedef __attribute__((ext_vector_type(8))) short short8;
typedef __attribute__((ext_vector_type(4))) float f32x4;

__device__ __forceinline__ uint32_t pk2bf(float a, float b) {
  uint32_t ua = __builtin_bit_cast(uint32_t, a);
  uint32_t ub = __builtin_bit_cast(uint32_t, b);
  ua = (ua + 0x7FFFu + ((ua >> 16) & 1u)) >> 16;
  ub = (ub + 0x7FFFu + ((ub >> 16) & 1u)) >> 16;
  return (ua & 0xFFFFu) | (ub << 16);
}
__device__ __forceinline__ uint16_t f2bf(float a) {
  uint32_t ua = __builtin_bit_cast(uint32_t, a);
  return (uint16_t)((ua + 0x7FFFu + ((ua >> 16) & 1u)) >> 16);
}
__device__ __forceinline__ float bflo(uint32_t w) { return __builtin_bit_cast(float, w << 16); }
__device__ __forceinline__ float bfhi(uint32_t w) { return __builtin_bit_cast(float, w & 0xFFFF0000u); }

__device__ __forceinline__ void gload_lds16(const void* g, void* l) {
  __builtin_amdgcn_global_load_lds(
      (const __attribute__((address_space(1))) uint32_t*)g,
      (__attribute__((address_space(3))) uint32_t*)l, 16, 0, 0);
}

// ---------------------------------------------------------------------------
// K0: convert Wq/Wk/Wv (512x512 f32 each) to bf16, contiguous Wb[3][262144].
// ---------------------------------------------------------------------------
__global__ __launch_bounds__(256) void k_cvtw(const float* __restrict__ Wq,
                                              const float* __restrict__ Wk,
                                              const float* __restrict__ Wv,
                                              uint16_t* __restrict__ Wb) {
  const int idx = blockIdx.x * 256 + threadIdx.x;  // 196608 float4 total
  const int sel = idx >> 16;                       // 65536 float4 per W
  const int e = idx & 65535;
  const float* src = (sel == 0) ? Wq : (sel == 1) ? Wk : Wv;
  const float4 v = *(const float4*)(src + (size_t)e * 4);
  uint2 p;
  p.x = pk2bf(v.x, v.y);
  p.y = pk2bf(v.z, v.w);
  *(uint2*)(Wb + (size_t)sel * 262144 + (size_t)e * 4) = p;
}

// ---------------------------------------------------------------------------
// K1: QKV projection GEMM, m97 structure. Tile 128x128, BK=64, 4 waves (2x2).
// A (f32) staged via global_load_lds (32KB); f32->bf16 at fragment load.
// B = Wb bf16 staged via global_load_lds (16KB). LDS ~49KB -> 3 blocks/CU.
// grid = 6144 = 512 rt x 3 proj x 4 ct, XCD-chunked, (proj,ct) fastest.
// Epilogue: bias, bf16 store, ||Q||^2/||K||^2, ks_sum.
// ---------------------------------------------------------------------------
__global__ __launch_bounds__(256, 3) void k_gemm_qkv(
    const float* __restrict__ qin, const float* __restrict__ sin_,
    const uint16_t* __restrict__ Wb,
    const float* __restrict__ bq, const float* __restrict__ bk,
    const float* __restrict__ bv,
    uint16_t* __restrict__ Qb, uint16_t* __restrict__ Kb, uint16_t* __restrict__ Vb,
    float* __restrict__ norms, float* __restrict__ ks_sum) {
  __shared__ float Asf[128 * 64];     // 32KB
  __shared__ uint16_t Bs[128 * 64];   // 16KB
  __shared__ float ksp[128];
  __shared__ float red[4];

  const int b0 = blockIdx.x;
  const int blk = (b0 & 7) * 768 + (b0 >> 3);  // XCD-chunked (6144 = 8*768)
  const int rt = blk / 12, rem = blk % 12;
  const int proj = rem >> 2, ct = rem & 3;
  const int row0 = rt * 128, cb = ct * 128;

  const float* A = proj ? sin_ : qin;
  const uint16_t* W = Wb + (size_t)proj * 262144;
  const float* Bi = (proj == 0) ? bq : (proj == 1) ? bk : bv;
  uint16_t* O = (proj == 0) ? Qb : (proj == 1) ? Kb : Vb;

  const int tid = threadIdx.x;
  const int lane = tid & 63;
  const int wv = tid >> 6;
  const int wr = wv >> 1, wc = wv & 1;
  const int l15 = lane & 15, lhi = lane >> 4;

  // staging lane decomposition (matches HW lds_base + lane*16 linear fill)
  const int a_r = lane >> 4, a_c = (lane & 15) * 4;   // f32 tile: 4 rows/issue
  const int b_r = lane >> 3, b_c = (lane & 7) * 8;    // bf16 tile: 8 rows/issue

  f32x4 acc[4][4];
#pragma unroll
  for (int m = 0; m < 4; ++m)
#pragma unroll
    for (int n = 0; n < 4; ++n) acc[m][n] = (f32x4){0.f, 0.f, 0.f, 0.f};

  for (int kt = 0; kt < 8; ++kt) {
    const int k0 = kt * 64;
#pragma unroll
    for (int i = 0; i < 8; ++i) {  // A: 8 issues/wave, 1KB each
      const int r = (wv * 8 + i) * 4 + a_r;
      gload_lds16(A + (size_t)(row0 + r) * 512 + k0 + a_c, &Asf[(wv * 8 + i) * 256]);
    }
#pragma unroll
    for (int i = 0; i < 4; ++i) {  // B: 4 issues/wave
      const int r = (wv * 4 + i) * 8 + b_r;
      gload_lds16(W + (size_t)(cb + r) * 512 + k0 + b_c, &Bs[(wv * 4 + i) * 512]);
    }
    __syncthreads();  // drains vmcnt (gload_lds) + lgkm
#pragma unroll
    for (int kk = 0; kk < 2; ++kk) {
      short8 a[4], b[4];
#pragma unroll
      for (int m = 0; m < 4; ++m) {
        const float* ar = &Asf[(wr * 64 + m * 16 + l15) * 64 + kk * 32 + lhi * 8];
        const f32x4 f0 = *(const f32x4*)ar;
        const f32x4 f1 = *(const f32x4*)(ar + 4);
        uint32_t* ap = (uint32_t*)&a[m];
        ap[0] = pk2bf(f0[0], f0[1]);
        ap[1] = pk2bf(f0[2], f0[3]);
        ap[2] = pk2bf(f1[0], f1[1]);
        ap[3] = pk2bf(f1[2], f1[3]);
      }
#pragma unroll
      for (int n = 0; n < 4; ++n)
        b[n] = *(const short8*)(&Bs[(wc * 64 + n * 16 + l15) * 64 + kk * 32 + lhi * 8]);
#pragma unroll
      for (int m = 0; m < 4; ++m)
#pragma unroll
        for (int n = 0; n < 4; ++n)
          acc[m][n] = __builtin_amdgcn_mfma_f32_16x16x32_bf16(a[m], b[n], acc[m][n], 0, 0, 0);
    }
    __syncthreads();
  }

  // Epilogue: bias, bf16 store, fused reductions.
  float nrm = 0.f;
  float cs[4] = {0.f, 0.f, 0.f, 0.f};
#pragma unroll
  for (int n = 0; n < 4; ++n) {
    const int colg = cb + wc * 64 + n * 16 + l15;
    const float bias = Bi[colg];
#pragma unroll
    for (int m = 0; m < 4; ++m) {
      const int rowb = row0 + wr * 64 + m * 16 + lhi * 4;
#pragma unroll
      for (int r = 0; r < 4; ++r) {
        const float v = acc[m][n][r] + bias;
        O[(size_t)(rowb + r) * 512 + colg] = f2bf(v);
        nrm += v * v;
        cs[n] += v;
      }
    }
  }
#pragma unroll
  for (int o = 32; o >= 1; o >>= 1) nrm += __shfl_xor(nrm, o, 64);
  if (lane == 0) red[wv] = nrm;
  if (tid < 128) ksp[tid] = 0.f;
  __syncthreads();
  if (proj == 1) {
#pragma unroll
    for (int n = 0; n < 4; ++n) {
      cs[n] += __shfl_xor(cs[n], 16, 64);
      cs[n] += __shfl_xor(cs[n], 32, 64);
    }
    if (lhi == 0) {
#pragma unroll
      for (int n = 0; n < 4; ++n) atomicAdd(&ksp[wc * 64 + n * 16 + l15], cs[n]);
    }
  }
  __syncthreads();
  if (tid == 0 && proj < 2)
    atomicAdd(&norms[proj], red[0] + red[1] + red[2] + red[3]);
  if (proj == 1 && tid < 128) atomicAdd(&ks_sum[cb + tid], ksp[tid]);
}

// ---------------------------------------------------------------------------
// K2: kvs[h][m][d] = sum_n K[n][h*64+m] * V[n][h*64+d]. 2 heads/block,
// 512 blocks (4 head-pairs x 128 chunks of 512 rows) for 2 blocks/CU overlap.
// ---------------------------------------------------------------------------
__global__ __launch_bounds__(256) void k_kvs(const uint16_t* __restrict__ Kb,
                                             const uint16_t* __restrict__ Vb,
                                             float* __restrict__ kvs) {
  __shared__ uint16_t Ks[64 * 128];
  __shared__ uint16_t Vs[64 * 128];
  const int tid = threadIdx.x;
  const int hp = blockIdx.x & 3;
  const int chunk = blockIdx.x >> 2;
  const int tm = tid >> 4, td = tid & 15;
  float acc0[4][4], acc1[4][4];
#pragma unroll
  for (int a = 0; a < 4; ++a)
#pragma unroll
    for (int b = 0; b < 4; ++b) { acc0[a][b] = 0.f; acc1[a][b] = 0.f; }

  for (int nb = 0; nb < 8; ++nb) {
    const int n0 = chunk * 512 + nb * 64;
#pragma unroll
    for (int i = 0; i < 4; ++i) {
      const int id = i * 256 + tid;
      const int row = id >> 4, c8 = id & 15;
      *(uint4*)(&Ks[row * 128 + c8 * 8]) =
          *(const uint4*)(Kb + (size_t)(n0 + row) * 512 + hp * 128 + c8 * 8);
      *(uint4*)(&Vs[row * 128 + c8 * 8]) =
          *(const uint4*)(Vb + (size_t)(n0 + row) * 512 + hp * 128 + c8 * 8);
    }
    __syncthreads();
    for (int nn = 0; nn < 64; ++nn) {
      const uint2 kw0 = *(const uint2*)(&Ks[nn * 128 + tm * 4]);
      const uint2 kw1 = *(const uint2*)(&Ks[nn * 128 + 64 + tm * 4]);
      const uint2 vw0 = *(const uint2*)(&Vs[nn * 128 + td * 4]);
      const uint2 vw1 = *(const uint2*)(&Vs[nn * 128 + 64 + td * 4]);
      const float km0[4] = {bflo(kw0.x), bfhi(kw0.x), bflo(kw0.y), bfhi(kw0.y)};
      const float km1[4] = {bflo(kw1.x), bfhi(kw1.x), bflo(kw1.y), bfhi(kw1.y)};
      const float vd0[4] = {bflo(vw0.x), bfhi(vw0.x), bflo(vw0.y), bfhi(vw0.y)};
      const float vd1[4] = {bflo(vw1.x), bfhi(vw1.x), bflo(vw1.y), bfhi(vw1.y)};
#pragma unroll
      for (int a = 0; a < 4; ++a)
#pragma unroll
        for (int b = 0; b < 4; ++b) {
          acc0[a][b] = fmaf(km0[a], vd0[b], acc0[a][b]);
          acc1[a][b] = fmaf(km1[a], vd1[b], acc1[a][b]);
        }
    }
    __syncthreads();
  }
  const int h0 = hp * 2;
#pragma unroll
  for (int a = 0; a < 4; ++a)
#pragma unroll
    for (int b = 0; b < 4; ++b) {
      atomicAdd(&kvs[(size_t)(h0 * 64 + tm * 4 + a) * 64 + td * 4 + b], acc0[a][b]);
      atomicAdd(&kvs[(size_t)((h0 + 1) * 64 + tm * 4 + a) * 64 + td * 4 + b], acc1[a][b]);
    }
}

// ---------------------------------------------------------------------------
// K2b: kvsT[d][k] = bf16(kvs[k][d])   (k = h*64+m in 0..511, d in 0..63)
// ---------------------------------------------------------------------------
__global__ void k_kvsT(const float* __restrict__ kvs, uint16_t* __restrict__ kvsT) {
  const int t = blockIdx.x * 256 + threadIdx.x;
  const int e0 = t * 4;
  const float4 v = *(const float4*)(kvs + e0);
  const int k = e0 >> 6, d0 = e0 & 63;
  kvsT[(size_t)(d0 + 0) * 512 + k] = f2bf(v.x);
  kvsT[(size_t)(d0 + 1) * 512 + k] = f2bf(v.y);
  kvsT[(size_t)(d0 + 2) * 512 + k] = f2bf(v.z);
  kvsT[(size_t)(d0 + 3) * 512 + k] = f2bf(v.w);
}

// ---------------------------------------------------------------------------
// K3 (fused): per block of 64 rows:
//   den prologue: den[r][h] = scale*(q . ks_sum_h) + N -> aS, bS in LDS
//   GEMM: out = (a-scaled Q) @ kvsT^T  +  (b-scaled V) @ I_blockdiag
//   (identity phase uses in-register constant B-fragments -> V-term free)
// A-fragments built directly from global (single-use, block panel L2-hot).
// B-fragments from global kvsT (128KB, L2-resident everywhere).
// ---------------------------------------------------------------------------
__global__ __launch_bounds__(256) void k_num(const uint16_t* __restrict__ Qb,
                                             const uint16_t* __restrict__ Vb,
                                             const uint16_t* __restrict__ kvsT,
                                             const float* __restrict__ ks_sum,
                                             const float* __restrict__ norms,
                                             float* __restrict__ out) {
  __shared__ float kss[512];
  __shared__ float aS[64 * 8];
  __shared__ float bS[64 * 8];
  const int tid = threadIdx.x, lane = tid & 63, wv = tid >> 6;
  const int l15 = lane & 15, lhi = lane >> 4;
  const int row0 = blockIdx.x * 64;

  kss[tid] = ks_sum[tid];
  kss[tid + 256] = ks_sum[tid + 256];
  __syncthreads();
  const float scale = 1.0f / (sqrtf(norms[0]) * sqrtf(norms[1]));

  {  // den: thread t -> row r = t>>2, heads (t&3)*2 and +1
    const int r = tid >> 2, h0 = (tid & 3) * 2;
#pragma unroll
    for (int hh = 0; hh < 2; ++hh) {
      const int h = h0 + hh;
      const uint16_t* q = Qb + (size_t)(row0 + r) * 512 + h * 64;
      const float* ks = &kss[h * 64];
      float dot = 0.f;
#pragma unroll
      for (int i = 0; i < 8; ++i) {
        const uint4 w = *(const uint4*)(q + i * 8);
        const uint32_t dw[4] = {w.x, w.y, w.z, w.w};
#pragma unroll
        for (int c = 0; c < 4; ++c) {
          dot = fmaf(bflo(dw[c]), ks[i * 8 + c * 2], dot);
          dot = fmaf(bfhi(dw[c]), ks[i * 8 + c * 2 + 1], dot);
        }
      }
      const float den = fmaf(scale, dot, 65536.0f);
      aS[r * 8 + h] = scale / (8.0f * den);
      bS[r * 8 + h] = 8192.0f / den;
    }
  }
  __syncthreads();

  // constant identity B-fragments: B[k][d] = (k%64 == d), k-slice (kk,lhi)
  short8 If[2][4];
#pragma unroll
  for (int kk = 0; kk < 2; ++kk)
#pragma unroll
    for (int n = 0; n < 4; ++n) {
      const int pos = n * 16 + l15 - kk * 32 - lhi * 8;  // hit if 0..7
      uint32_t* p = (uint32_t*)&If[kk][n];
#pragma unroll
      for (int jw = 0; jw < 4; ++jw)
        p[jw] = ((pos >> 1) == jw) ? ((pos & 1) ? 0x3F800000u : 0x00003F80u) : 0u;
    }

  const int myrow = row0 + wv * 16 + l15;
  f32x4 acc[4];
#pragma unroll
  for (int n = 0; n < 4; ++n) acc[n] = (f32x4){0.f, 0.f, 0.f, 0.f};

  // Phase 1: a-scaled Q against kvsT   (k = h*64 + kk*32 + lhi*8 + j)
  for (int h = 0; h < 8; ++h) {
    const float sc = aS[(wv * 16 + l15) * 8 + h];
#pragma unroll
    for (int kk = 0; kk < 2; ++kk) {
      const uint4 w = *(const uint4*)(Qb + (size_t)myrow * 512 + h * 64 + kk * 32 + lhi * 8);
      const uint32_t dw[4] = {w.x, w.y, w.z, w.w};
      short8 af;
      uint32_t* ap = (uint32_t*)&af;
#pragma unroll
      for (int c = 0; c < 4; ++c) ap[c] = pk2bf(bflo(dw[c]) * sc, bfhi(dw[c]) * sc);
#pragma unroll
      for (int n = 0; n < 4; ++n) {
        const short8 bf =
            *(const short8*)(kvsT + (size_t)(n * 16 + l15) * 512 + h * 64 + kk * 32 + lhi * 8);
        acc[n] = __builtin_amdgcn_mfma_f32_16x16x32_bf16(af, bf, acc[n], 0, 0, 0);
      }
    }
  }
  // Phase 2: b-scaled V against block-diag identity
  for (int h = 0; h < 8; ++h) {
    const float sc = bS[(wv * 16 + l15) * 8 + h];
#pragma unroll
    for (int kk = 0; kk < 2; ++kk) {
      const uint4 w = *(const uint4*)(Vb + (size_t)myrow * 512 + h * 64 + kk * 32 + lhi * 8);
      const uint32_t dw[4] = {w.x, w.y, w.z, w.w};
      short8 af;
      uint32_t* ap = (uint32_t*)&af;
#pragma unroll
      for (int c = 0; c < 4; ++c) ap[c] = pk2bf(bflo(dw[c]) * sc, bfhi(dw[c]) * sc);
#pragma unroll
      for (int n = 0; n < 4; ++n)
        acc[n] = __builtin_amdgcn_mfma_f32_16x16x32_bf16(af, If[kk][n], acc[n], 0, 0, 0);
    }
  }

#pragma unroll
  for (int n = 0; n < 4; ++n)
#pragma unroll
    for (int j = 0; j < 4; ++j)
      out[(size_t)(row0 + wv * 16 + lhi * 4 + j) * 64 + n * 16 + l15] = acc[n][j];
}

// ---------------------------------------------------------------------------
extern "C" void kernel_launch(void* const* d_in, const int* in_sizes, int n_in,
                              void* d_out, int out_size, void* d_ws, size_t ws_size,
                              hipStream_t stream) {
  const float* qin = (const float*)d_in[0];
  const float* sin_ = (const float*)d_in[1];
  const float* Wq = (const float*)d_in[2];
  const float* bq = (const float*)d_in[3];
  const float* Wk = (const float*)d_in[4];
  const float* bk = (const float*)d_in[5];
  const float* Wv = (const float*)d_in[6];
  const float* bv = (const float*)d_in[7];
  float* out = (float*)d_out;

  char* ws = (char*)d_ws;
  float* kvs = (float*)ws;                          // 128KB
  float* ks_sum = (float*)(ws + 131072);            // 2KB
  float* norms = (float*)(ws + 133120);             // 8B
  uint16_t* kvsT = (uint16_t*)(ws + 262144);        // 64KB
  uint16_t* Wb = (uint16_t*)(ws + 393216);          // 1.5MB
  uint16_t* Qb = (uint16_t*)(ws + (2ull << 20));                     // 64MB
  uint16_t* Kb = (uint16_t*)(ws + (2ull << 20) + 67108864ull);       // 64MB
  uint16_t* Vb = (uint16_t*)(ws + (2ull << 20) + 134217728ull);      // 64MB

  hipMemsetAsync(d_ws, 0, 133128, stream);  // kvs, ks_sum, norms

  k_cvtw<<<dim3(768), dim3(256), 0, stream>>>(Wq, Wk, Wv, Wb);
  k_gemm_qkv<<<dim3(6144), dim3(256), 0, stream>>>(qin, sin_, Wb, bq, bk, bv,
                                                   Qb, Kb, Vb, norms, ks_sum);
  k_kvs<<<dim3(512), dim3(256), 0, stream>>>(Kb, Vb, kvs);
  k_kvsT<<<dim3(32), dim3(256), 0, stream>>>(kvs, kvsT);
  k_num<<<dim3(1024), dim3(256), 0, stream>>>(Qb, Vb, kvsT, ks_sum, norms, out);
}

// Round 5
// 415.310 us; speedup vs baseline: 1.5442x; 1.0949x over previous
//
#include <hip/hip_runtime.h>
#include <stdint.h>

typedef __attribute__((ext_vector_type(8))) short short8;
typedef __attribute__((ext_vector_type(4))) float f32x4;

__device__ __forceinline__ uint32_t pk2bf(float a, float b) {
  uint32_t ua = __builtin_bit_cast(uint32_t, a);
  uint32_t ub = __builtin_bit_cast(uint32_t, b);
  ua = (ua + 0x7FFFu + ((ua >> 16) & 1u)) >> 16;
  ub = (ub + 0x7FFFu + ((ub >> 16) & 1u)) >> 16;
  return (ua & 0xFFFFu) | (ub << 16);
}
__device__ __forceinline__ uint16_t f2bf(float a) {
  uint32_t ua = __builtin_bit_cast(uint32_t, a);
  return (uint16_t)((ua + 0x7FFFu + ((ua >> 16) & 1u)) >> 16);
}
__device__ __forceinline__ float bflo(uint32_t w) { return __builtin_bit_cast(float, w << 16); }
__device__ __forceinline__ float bfhi(uint32_t w) { return __builtin_bit_cast(float, w & 0xFFFF0000u); }

__device__ __forceinline__ void gload_lds16(const void* g, void* l) {
  __builtin_amdgcn_global_load_lds(
      (const __attribute__((address_space(1))) uint32_t*)g,
      (__attribute__((address_space(3))) uint32_t*)l, 16, 0, 0);
}

// ---------------------------------------------------------------------------
// K0: convert Wq/Wk/Wv (512x512 f32 each) to bf16, contiguous Wb[3][262144].
// ---------------------------------------------------------------------------
__global__ __launch_bounds__(256) void k_cvtw(const float* __restrict__ Wq,
                                              const float* __restrict__ Wk,
                                              const float* __restrict__ Wv,
                                              uint16_t* __restrict__ Wb) {
  const int idx = blockIdx.x * 256 + threadIdx.x;  // 196608 float4 total
  const int sel = idx >> 16;                       // 65536 float4 per W
  const int e = idx & 65535;
  const float* src = (sel == 0) ? Wq : (sel == 1) ? Wk : Wv;
  const float4 v = *(const float4*)(src + (size_t)e * 4);
  uint2 p;
  p.x = pk2bf(v.x, v.y);
  p.y = pk2bf(v.z, v.w);
  *(uint2*)(Wb + (size_t)sel * 262144 + (size_t)e * 4) = p;
}

// ---------------------------------------------------------------------------
// K1: QKV projection GEMM. Tile 128x128, BK=64, 4 waves (2x2 of 64x64).
// A (f32) + B (bf16) staged via global_load_lds with SOURCE pre-swizzle
// (rule #21: linear LDS dest + inverse-permuted global src + XOR'd read).
// XOR (row&7)<<4 -> fragment ds_reads are 2-way max (free).
// f32->bf16 conversion happens at fragment load (VALU, overlapped).
// ---------------------------------------------------------------------------
__global__ __launch_bounds__(256, 3) void k_gemm_qkv(
    const float* __restrict__ qin, const float* __restrict__ sin_,
    const uint16_t* __restrict__ Wb,
    const float* __restrict__ bq, const float* __restrict__ bk,
    const float* __restrict__ bv,
    uint16_t* __restrict__ Qb, uint16_t* __restrict__ Kb, uint16_t* __restrict__ Vb,
    float* __restrict__ norms, float* __restrict__ ks_sum) {
  __shared__ float Asf[128 * 64];     // 32KB, swizzled layout
  __shared__ uint16_t Bs[128 * 64];   // 16KB, swizzled layout
  __shared__ float ksp[128];
  __shared__ float red[4];

  const int b0 = blockIdx.x;
  const int blk = (b0 & 7) * 768 + (b0 >> 3);  // XCD-chunked (6144 = 8*768)
  const int rt = blk / 12, rem = blk % 12;
  const int proj = rem >> 2, ct = rem & 3;
  const int row0 = rt * 128, cb = ct * 128;

  const float* A = proj ? sin_ : qin;
  const uint16_t* W = Wb + (size_t)proj * 262144;
  const float* Bi = (proj == 0) ? bq : (proj == 1) ? bk : bv;
  uint16_t* O = (proj == 0) ? Qb : (proj == 1) ? Kb : Vb;

  const int tid = threadIdx.x;
  const int lane = tid & 63;
  const int wv = tid >> 6;
  const int wr = wv >> 1, wc = wv & 1;
  const int l15 = lane & 15, lhi = lane >> 4;

  f32x4 acc[4][4];
#pragma unroll
  for (int m = 0; m < 4; ++m)
#pragma unroll
    for (int n = 0; n < 4; ++n) acc[m][n] = (f32x4){0.f, 0.f, 0.f, 0.f};

  for (int kt = 0; kt < 8; ++kt) {
    const int k0 = kt * 64;
#pragma unroll
    for (int i = 0; i < 8; ++i) {  // A: 8 issues/wave, 1KB each (4 rows)
      const int arow = (wv * 8 + i) * 4 + (lane >> 4);
      const int ac16 = (lane & 15) ^ (arow & 7);  // inverse swizzle on source
      gload_lds16(A + (size_t)(row0 + arow) * 512 + k0 + ac16 * 4,
                  &Asf[(wv * 8 + i) * 256]);
    }
#pragma unroll
    for (int i = 0; i < 4; ++i) {  // B: 4 issues/wave, 1KB each (8 rows)
      const int brow = (wv * 4 + i) * 8 + (lane >> 3);
      const int bc16 = (lane & 7) ^ (brow & 7);
      gload_lds16(W + (size_t)(cb + brow) * 512 + k0 + bc16 * 8,
                  &Bs[(wv * 4 + i) * 512]);
    }
    __syncthreads();  // drains vmcnt (gload_lds) + lgkm
#pragma unroll
    for (int kk = 0; kk < 2; ++kk) {
      short8 a[4], b[4];
#pragma unroll
      for (int m = 0; m < 4; ++m) {
        const int r = wr * 64 + m * 16 + l15;
        const int base = r * 256 + kk * 128 + lhi * 32;
        const int sw = (r & 7) << 4;
        const f32x4 f0 = *(const f32x4*)((const char*)Asf + (base ^ sw));
        const f32x4 f1 = *(const f32x4*)((const char*)Asf + ((base + 16) ^ sw));
        uint32_t* ap = (uint32_t*)&a[m];
        ap[0] = pk2bf(f0[0], f0[1]);
        ap[1] = pk2bf(f0[2], f0[3]);
        ap[2] = pk2bf(f1[0], f1[1]);
        ap[3] = pk2bf(f1[2], f1[3]);
      }
#pragma unroll
      for (int n = 0; n < 4; ++n) {
        const int c = wc * 64 + n * 16 + l15;
        const int bo = (c * 128 + kk * 64 + lhi * 16) ^ ((c & 7) << 4);
        b[n] = *(const short8*)((const char*)Bs + bo);
      }
#pragma unroll
      for (int m = 0; m < 4; ++m)
#pragma unroll
        for (int n = 0; n < 4; ++n)
          acc[m][n] = __builtin_amdgcn_mfma_f32_16x16x32_bf16(a[m], b[n], acc[m][n], 0, 0, 0);
    }
    __syncthreads();
  }

  // Epilogue: bias, bf16 store, fused reductions.
  float nrm = 0.f;
  float cs[4] = {0.f, 0.f, 0.f, 0.f};
#pragma unroll
  for (int n = 0; n < 4; ++n) {
    const int colg = cb + wc * 64 + n * 16 + l15;
    const float bias = Bi[colg];
#pragma unroll
    for (int m = 0; m < 4; ++m) {
      const int rowb = row0 + wr * 64 + m * 16 + lhi * 4;
#pragma unroll
      for (int r = 0; r < 4; ++r) {
        const float v = acc[m][n][r] + bias;
        O[(size_t)(rowb + r) * 512 + colg] = f2bf(v);
        nrm += v * v;
        cs[n] += v;
      }
    }
  }
#pragma unroll
  for (int o = 32; o >= 1; o >>= 1) nrm += __shfl_xor(nrm, o, 64);
  if (lane == 0) red[wv] = nrm;
  if (tid < 128) ksp[tid] = 0.f;
  __syncthreads();
  if (proj == 1) {
#pragma unroll
    for (int n = 0; n < 4; ++n) {
      cs[n] += __shfl_xor(cs[n], 16, 64);
      cs[n] += __shfl_xor(cs[n], 32, 64);
    }
    if (lhi == 0) {
#pragma unroll
      for (int n = 0; n < 4; ++n) atomicAdd(&ksp[wc * 64 + n * 16 + l15], cs[n]);
    }
  }
  __syncthreads();
  if (tid == 0 && proj < 2)
    atomicAdd(&norms[proj], red[0] + red[1] + red[2] + red[3]);
  if (proj == 1 && tid < 128) atomicAdd(&ks_sum[cb + tid], ksp[tid]);
}

// ---------------------------------------------------------------------------
// K2: kvs[h][m][d] = sum_n K[n][h*64+m] * V[n][h*64+d]. 2 heads/block,
// 1024 blocks (4 head-pairs x 256 chunks of 256 rows) -> 4 blocks/CU.
// ---------------------------------------------------------------------------
__global__ __launch_bounds__(256) void k_kvs(const uint16_t* __restrict__ Kb,
                                             const uint16_t* __restrict__ Vb,
                                             float* __restrict__ kvs) {
  __shared__ uint16_t Ks[64 * 128];
  __shared__ uint16_t Vs[64 * 128];
  const int tid = threadIdx.x;
  const int hp = blockIdx.x & 3;
  const int chunk = blockIdx.x >> 2;
  const int tm = tid >> 4, td = tid & 15;
  float acc0[4][4], acc1[4][4];
#pragma unroll
  for (int a = 0; a < 4; ++a)
#pragma unroll
    for (int b = 0; b < 4; ++b) { acc0[a][b] = 0.f; acc1[a][b] = 0.f; }

  for (int nb = 0; nb < 4; ++nb) {
    const int n0 = chunk * 256 + nb * 64;
#pragma unroll
    for (int i = 0; i < 4; ++i) {
      const int id = i * 256 + tid;
      const int row = id >> 4, c8 = id & 15;
      *(uint4*)(&Ks[row * 128 + c8 * 8]) =
          *(const uint4*)(Kb + (size_t)(n0 + row) * 512 + hp * 128 + c8 * 8);
      *(uint4*)(&Vs[row * 128 + c8 * 8]) =
          *(const uint4*)(Vb + (size_t)(n0 + row) * 512 + hp * 128 + c8 * 8);
    }
    __syncthreads();
    for (int nn = 0; nn < 64; ++nn) {
      const uint2 kw0 = *(const uint2*)(&Ks[nn * 128 + tm * 4]);
      const uint2 kw1 = *(const uint2*)(&Ks[nn * 128 + 64 + tm * 4]);
      const uint2 vw0 = *(const uint2*)(&Vs[nn * 128 + td * 4]);
      const uint2 vw1 = *(const uint2*)(&Vs[nn * 128 + 64 + td * 4]);
      const float km0[4] = {bflo(kw0.x), bfhi(kw0.x), bflo(kw0.y), bfhi(kw0.y)};
      const float km1[4] = {bflo(kw1.x), bfhi(kw1.x), bflo(kw1.y), bfhi(kw1.y)};
      const float vd0[4] = {bflo(vw0.x), bfhi(vw0.x), bflo(vw0.y), bfhi(vw0.y)};
      const float vd1[4] = {bflo(vw1.x), bfhi(vw1.x), bflo(vw1.y), bfhi(vw1.y)};
#pragma unroll
      for (int a = 0; a < 4; ++a)
#pragma unroll
        for (int b = 0; b < 4; ++b) {
          acc0[a][b] = fmaf(km0[a], vd0[b], acc0[a][b]);
          acc1[a][b] = fmaf(km1[a], vd1[b], acc1[a][b]);
        }
    }
    __syncthreads();
  }
  const int h0 = hp * 2;
#pragma unroll
  for (int a = 0; a < 4; ++a)
#pragma unroll
    for (int b = 0; b < 4; ++b) {
      atomicAdd(&kvs[(size_t)(h0 * 64 + tm * 4 + a) * 64 + td * 4 + b], acc0[a][b]);
      atomicAdd(&kvs[(size_t)((h0 + 1) * 64 + tm * 4 + a) * 64 + td * 4 + b], acc1[a][b]);
    }
}

// ---------------------------------------------------------------------------
// K2b: kvsT[d][k] = bf16(kvs[k][d])   (k = h*64+m in 0..511, d in 0..63)
// ---------------------------------------------------------------------------
__global__ void k_kvsT(const float* __restrict__ kvs, uint16_t* __restrict__ kvsT) {
  const int t = blockIdx.x * 256 + threadIdx.x;
  const int e0 = t * 4;
  const float4 v = *(const float4*)(kvs + e0);
  const int k = e0 >> 6, d0 = e0 & 63;
  kvsT[(size_t)(d0 + 0) * 512 + k] = f2bf(v.x);
  kvsT[(size_t)(d0 + 1) * 512 + k] = f2bf(v.y);
  kvsT[(size_t)(d0 + 2) * 512 + k] = f2bf(v.z);
  kvsT[(size_t)(d0 + 3) * 512 + k] = f2bf(v.w);
}

// ---------------------------------------------------------------------------
// K3 (fused): den prologue -> aS,bS; out = (aQ)@kvsT^T + (bV)@I_blockdiag.
// ---------------------------------------------------------------------------
__global__ __launch_bounds__(256) void k_num(const uint16_t* __restrict__ Qb,
                                             const uint16_t* __restrict__ Vb,
                                             const uint16_t* __restrict__ kvsT,
                                             const float* __restrict__ ks_sum,
                                             const float* __restrict__ norms,
                                             float* __restrict__ out) {
  __shared__ float kss[512];
  __shared__ float aS[64 * 8];
  __shared__ float bS[64 * 8];
  const int tid = threadIdx.x, lane = tid & 63, wv = tid >> 6;
  const int l15 = lane & 15, lhi = lane >> 4;
  const int row0 = blockIdx.x * 64;

  kss[tid] = ks_sum[tid];
  kss[tid + 256] = ks_sum[tid + 256];
  __syncthreads();
  const float scale = 1.0f / (sqrtf(norms[0]) * sqrtf(norms[1]));

  {  // den: thread t -> row r = t>>2, heads (t&3)*2 and +1
    const int r = tid >> 2, h0 = (tid & 3) * 2;
#pragma unroll
    for (int hh = 0; hh < 2; ++hh) {
      const int h = h0 + hh;
      const uint16_t* q = Qb + (size_t)(row0 + r) * 512 + h * 64;
      const float* ks = &kss[h * 64];
      float dot = 0.f;
#pragma unroll
      for (int i = 0; i < 8; ++i) {
        const uint4 w = *(const uint4*)(q + i * 8);
        const uint32_t dw[4] = {w.x, w.y, w.z, w.w};
#pragma unroll
        for (int c = 0; c < 4; ++c) {
          dot = fmaf(bflo(dw[c]), ks[i * 8 + c * 2], dot);
          dot = fmaf(bfhi(dw[c]), ks[i * 8 + c * 2 + 1], dot);
        }
      }
      const float den = fmaf(scale, dot, 65536.0f);
      aS[r * 8 + h] = scale / (8.0f * den);
      bS[r * 8 + h] = 8192.0f / den;
    }
  }
  __syncthreads();

  // constant identity B-fragments: B[k][d] = (k%64 == d), k-slice (kk,lhi)
  short8 If[2][4];
#pragma unroll
  for (int kk = 0; kk < 2; ++kk)
#pragma unroll
    for (int n = 0; n < 4; ++n) {
      const int pos = n * 16 + l15 - kk * 32 - lhi * 8;  // hit if 0..7
      uint32_t* p = (uint32_t*)&If[kk][n];
#pragma unroll
      for (int jw = 0; jw < 4; ++jw)
        p[jw] = ((pos >> 1) == jw) ? ((pos & 1) ? 0x3F800000u : 0x00003F80u) : 0u;
    }

  const int myrow = row0 + wv * 16 + l15;
  f32x4 acc[4];
#pragma unroll
  for (int n = 0; n < 4; ++n) acc[n] = (f32x4){0.f, 0.f, 0.f, 0.f};

  // Phase 1: a-scaled Q against kvsT   (k = h*64 + kk*32 + lhi*8 + j)
  for (int h = 0; h < 8; ++h) {
    const float sc = aS[(wv * 16 + l15) * 8 + h];
#pragma unroll
    for (int kk = 0; kk < 2; ++kk) {
      const uint4 w = *(const uint4*)(Qb + (size_t)myrow * 512 + h * 64 + kk * 32 + lhi * 8);
      const uint32_t dw[4] = {w.x, w.y, w.z, w.w};
      short8 af;
      uint32_t* ap = (uint32_t*)&af;
#pragma unroll
      for (int c = 0; c < 4; ++c) ap[c] = pk2bf(bflo(dw[c]) * sc, bfhi(dw[c]) * sc);
#pragma unroll
      for (int n = 0; n < 4; ++n) {
        const short8 bf =
            *(const short8*)(kvsT + (size_t)(n * 16 + l15) * 512 + h * 64 + kk * 32 + lhi * 8);
        acc[n] = __builtin_amdgcn_mfma_f32_16x16x32_bf16(af, bf, acc[n], 0, 0, 0);
      }
    }
  }
  // Phase 2: b-scaled V against block-diag identity
  for (int h = 0; h < 8; ++h) {
    const float sc = bS[(wv * 16 + l15) * 8 + h];
#pragma unroll
    for (int kk = 0; kk < 2; ++kk) {
      const uint4 w = *(const uint4*)(Vb + (size_t)myrow * 512 + h * 64 + kk * 32 + lhi * 8);
      const uint32_t dw[4] = {w.x, w.y, w.z, w.w};
      short8 af;
      uint32_t* ap = (uint32_t*)&af;
#pragma unroll
      for (int c = 0; c < 4; ++c) ap[c] = pk2bf(bflo(dw[c]) * sc, bfhi(dw[c]) * sc);
#pragma unroll
      for (int n = 0; n < 4; ++n)
        acc[n] = __builtin_amdgcn_mfma_f32_16x16x32_bf16(af, If[kk][n], acc[n], 0, 0, 0);
    }
  }

#pragma unroll
  for (int n = 0; n < 4; ++n)
#pragma unroll
    for (int j = 0; j < 4; ++j)
      out[(size_t)(row0 + wv * 16 + lhi * 4 + j) * 64 + n * 16 + l15] = acc[n][j];
}

// ---------------------------------------------------------------------------
extern "C" void kernel_launch(void* const* d_in, const int* in_sizes, int n_in,
                              void* d_out, int out_size, void* d_ws, size_t ws_size,
                              hipStream_t stream) {
  const float* qin = (const float*)d_in[0];
  const float* sin_ = (const float*)d_in[1];
  const float* Wq = (const float*)d_in[2];
  const float* bq = (const float*)d_in[3];
  const float* Wk = (const float*)d_in[4];
  const float* bk = (const float*)d_in[5];
  const float* Wv = (const float*)d_in[6];
  const float* bv = (const float*)d_in[7];
  float* out = (float*)d_out;

  char* ws = (char*)d_ws;
  float* kvs = (float*)ws;                          // 128KB
  float* ks_sum = (float*)(ws + 131072);            // 2KB
  float* norms = (float*)(ws + 133120);             // 8B
  uint16_t* kvsT = (uint16_t*)(ws + 262144);        // 64KB
  uint16_t* Wb = (uint16_t*)(ws + 393216);          // 1.5MB
  uint16_t* Qb = (uint16_t*)(ws + (2ull << 20));                     // 64MB
  uint16_t* Kb = (uint16_t*)(ws + (2ull << 20) + 67108864ull);       // 64MB
  uint16_t* Vb = (uint16_t*)(ws + (2ull << 20) + 134217728ull);      // 64MB

  hipMemsetAsync(d_ws, 0, 133128, stream);  // kvs, ks_sum, norms

  k_cvtw<<<dim3(768), dim3(256), 0, stream>>>(Wq, Wk, Wv, Wb);
  k_gemm_qkv<<<dim3(6144), dim3(256), 0, stream>>>(qin, sin_, Wb, bq, bk, bv,
                                                   Qb, Kb, Vb, norms, ks_sum);
  k_kvs<<<dim3(1024), dim3(256), 0, stream>>>(Kb, Vb, kvs);
  k_kvsT<<<dim3(32), dim3(256), 0, stream>>>(kvs, kvsT);
  k_num<<<dim3(1024), dim3(256), 0, stream>>>(Qb, Vb, kvsT, ks_sum, norms, out);
}

// Round 6
// 405.084 us; speedup vs baseline: 1.5832x; 1.0252x over previous
//
#include <hip/hip_runtime.h>
#include <stdint.h>

typedef __attribute__((ext_vector_type(8))) short short8;
typedef __attribute__((ext_vector_type(4))) float f32x4;

// HW packed f32->bf16 (RNE): dst.lo = bf16(a), dst.hi = bf16(b). gfx950.
__device__ __forceinline__ uint32_t pk2bf(float a, float b) {
  uint32_t r;
  asm("v_cvt_pk_bf16_f32 %0, %1, %2" : "=v"(r) : "v"(a), "v"(b));
  return r;
}
__device__ __forceinline__ uint16_t f2bf(float a) {
  uint32_t ua = __builtin_bit_cast(uint32_t, a);
  return (uint16_t)((ua + 0x7FFFu + ((ua >> 16) & 1u)) >> 16);
}
__device__ __forceinline__ float bflo(uint32_t w) { return __builtin_bit_cast(float, w << 16); }
__device__ __forceinline__ float bfhi(uint32_t w) { return __builtin_bit_cast(float, w & 0xFFFF0000u); }

__device__ __forceinline__ void gload_lds16(const void* g, void* l) {
  __builtin_amdgcn_global_load_lds(
      (const __attribute__((address_space(1))) uint32_t*)g,
      (__attribute__((address_space(3))) uint32_t*)l, 16, 0, 0);
}

// ---------------------------------------------------------------------------
// K0: convert Wq/Wk/Wv (512x512 f32 each) to bf16, contiguous Wb[3][262144].
// ---------------------------------------------------------------------------
__global__ __launch_bounds__(256) void k_cvtw(const float* __restrict__ Wq,
                                              const float* __restrict__ Wk,
                                              const float* __restrict__ Wv,
                                              uint16_t* __restrict__ Wb) {
  const int idx = blockIdx.x * 256 + threadIdx.x;  // 196608 float4 total
  const int sel = idx >> 16;                       // 65536 float4 per W
  const int e = idx & 65535;
  const float* src = (sel == 0) ? Wq : (sel == 1) ? Wk : Wv;
  const float4 v = *(const float4*)(src + (size_t)e * 4);
  uint2 p;
  p.x = pk2bf(v.x, v.y);
  p.y = pk2bf(v.z, v.w);
  *(uint2*)(Wb + (size_t)sel * 262144 + (size_t)e * 4) = p;
}

// ---------------------------------------------------------------------------
// K1: QKV projection GEMM. Tile 128x128, BK=64, 4 waves (2x2 of 64x64).
// A (f32) + B (bf16) staged via global_load_lds with SOURCE pre-swizzle
// (linear LDS dest + inverse-permuted global src + XOR'd read).
// f32->bf16 at fragment load via v_cvt_pk_bf16_f32 (1 inst / 2 elements).
// ---------------------------------------------------------------------------
__global__ __launch_bounds__(256, 3) void k_gemm_qkv(
    const float* __restrict__ qin, const float* __restrict__ sin_,
    const uint16_t* __restrict__ Wb,
    const float* __restrict__ bq, const float* __restrict__ bk,
    const float* __restrict__ bv,
    uint16_t* __restrict__ Qb, uint16_t* __restrict__ Kb, uint16_t* __restrict__ Vb,
    float* __restrict__ norms, float* __restrict__ ks_sum) {
  __shared__ float Asf[128 * 64];     // 32KB, swizzled layout
  __shared__ uint16_t Bs[128 * 64];   // 16KB, swizzled layout
  __shared__ float ksp[128];
  __shared__ float red[4];

  const int b0 = blockIdx.x;
  const int blk = (b0 & 7) * 768 + (b0 >> 3);  // XCD-chunked (6144 = 8*768)
  const int rt = blk / 12, rem = blk % 12;
  const int proj = rem >> 2, ct = rem & 3;
  const int row0 = rt * 128, cb = ct * 128;

  const float* A = proj ? sin_ : qin;
  const uint16_t* W = Wb + (size_t)proj * 262144;
  const float* Bi = (proj == 0) ? bq : (proj == 1) ? bk : bv;
  uint16_t* O = (proj == 0) ? Qb : (proj == 1) ? Kb : Vb;

  const int tid = threadIdx.x;
  const int lane = tid & 63;
  const int wv = tid >> 6;
  const int wr = wv >> 1, wc = wv & 1;
  const int l15 = lane & 15, lhi = lane >> 4;

  f32x4 acc[4][4];
#pragma unroll
  for (int m = 0; m < 4; ++m)
#pragma unroll
    for (int n = 0; n < 4; ++n) acc[m][n] = (f32x4){0.f, 0.f, 0.f, 0.f};

  for (int kt = 0; kt < 8; ++kt) {
    const int k0 = kt * 64;
#pragma unroll
    for (int i = 0; i < 8; ++i) {  // A: 8 issues/wave, 1KB each (4 rows)
      const int arow = (wv * 8 + i) * 4 + (lane >> 4);
      const int ac16 = (lane & 15) ^ (arow & 7);  // inverse swizzle on source
      gload_lds16(A + (size_t)(row0 + arow) * 512 + k0 + ac16 * 4,
                  &Asf[(wv * 8 + i) * 256]);
    }
#pragma unroll
    for (int i = 0; i < 4; ++i) {  // B: 4 issues/wave, 1KB each (8 rows)
      const int brow = (wv * 4 + i) * 8 + (lane >> 3);
      const int bc16 = (lane & 7) ^ (brow & 7);
      gload_lds16(W + (size_t)(cb + brow) * 512 + k0 + bc16 * 8,
                  &Bs[(wv * 4 + i) * 512]);
    }
    __syncthreads();  // drains vmcnt (gload_lds) + lgkm
#pragma unroll
    for (int kk = 0; kk < 2; ++kk) {
      short8 a[4], b[4];
#pragma unroll
      for (int m = 0; m < 4; ++m) {
        const int r = wr * 64 + m * 16 + l15;
        const int base = r * 256 + kk * 128 + lhi * 32;
        const int sw = (r & 7) << 4;
        const f32x4 f0 = *(const f32x4*)((const char*)Asf + (base ^ sw));
        const f32x4 f1 = *(const f32x4*)((const char*)Asf + ((base + 16) ^ sw));
        uint32_t* ap = (uint32_t*)&a[m];
        ap[0] = pk2bf(f0[0], f0[1]);
        ap[1] = pk2bf(f0[2], f0[3]);
        ap[2] = pk2bf(f1[0], f1[1]);
        ap[3] = pk2bf(f1[2], f1[3]);
      }
#pragma unroll
      for (int n = 0; n < 4; ++n) {
        const int c = wc * 64 + n * 16 + l15;
        const int bo = (c * 128 + kk * 64 + lhi * 16) ^ ((c & 7) << 4);
        b[n] = *(const short8*)((const char*)Bs + bo);
      }
#pragma unroll
      for (int m = 0; m < 4; ++m)
#pragma unroll
        for (int n = 0; n < 4; ++n)
          acc[m][n] = __builtin_amdgcn_mfma_f32_16x16x32_bf16(a[m], b[n], acc[m][n], 0, 0, 0);
    }
    __syncthreads();
  }

  // Epilogue: bias, bf16 store, fused reductions.
  float nrm = 0.f;
  float cs[4] = {0.f, 0.f, 0.f, 0.f};
#pragma unroll
  for (int n = 0; n < 4; ++n) {
    const int colg = cb + wc * 64 + n * 16 + l15;
    const float bias = Bi[colg];
#pragma unroll
    for (int m = 0; m < 4; ++m) {
      const int rowb = row0 + wr * 64 + m * 16 + lhi * 4;
#pragma unroll
      for (int r = 0; r < 4; ++r) {
        const float v = acc[m][n][r] + bias;
        O[(size_t)(rowb + r) * 512 + colg] = f2bf(v);
        nrm += v * v;
        cs[n] += v;
      }
    }
  }
#pragma unroll
  for (int o = 32; o >= 1; o >>= 1) nrm += __shfl_xor(nrm, o, 64);
  if (lane == 0) red[wv] = nrm;
  if (tid < 128) ksp[tid] = 0.f;
  __syncthreads();
  if (proj == 1) {
#pragma unroll
    for (int n = 0; n < 4; ++n) {
      cs[n] += __shfl_xor(cs[n], 16, 64);
      cs[n] += __shfl_xor(cs[n], 32, 64);
    }
    if (lhi == 0) {
#pragma unroll
      for (int n = 0; n < 4; ++n) atomicAdd(&ksp[wc * 64 + n * 16 + l15], cs[n]);
    }
  }
  __syncthreads();
  if (tid == 0 && proj < 2)
    atomicAdd(&norms[proj], red[0] + red[1] + red[2] + red[3]);
  if (proj == 1 && tid < 128) atomicAdd(&ks_sum[cb + tid], ksp[tid]);
}

// ---------------------------------------------------------------------------
// K2: kvs[h][m][d] = sum_n K[n][h*64+m] * V[n][h*64+d]. 2 heads/block,
// 1024 blocks (4 head-pairs x 256 chunks of 256 rows) -> 4 blocks/CU.
// ---------------------------------------------------------------------------
__global__ __launch_bounds__(256) void k_kvs(const uint16_t* __restrict__ Kb,
                                             const uint16_t* __restrict__ Vb,
                                             float* __restrict__ kvs) {
  __shared__ uint16_t Ks[64 * 128];
  __shared__ uint16_t Vs[64 * 128];
  const int tid = threadIdx.x;
  const int hp = blockIdx.x & 3;
  const int chunk = blockIdx.x >> 2;
  const int tm = tid >> 4, td = tid & 15;
  float acc0[4][4], acc1[4][4];
#pragma unroll
  for (int a = 0; a < 4; ++a)
#pragma unroll
    for (int b = 0; b < 4; ++b) { acc0[a][b] = 0.f; acc1[a][b] = 0.f; }

  for (int nb = 0; nb < 4; ++nb) {
    const int n0 = chunk * 256 + nb * 64;
#pragma unroll
    for (int i = 0; i < 4; ++i) {
      const int id = i * 256 + tid;
      const int row = id >> 4, c8 = id & 15;
      *(uint4*)(&Ks[row * 128 + c8 * 8]) =
          *(const uint4*)(Kb + (size_t)(n0 + row) * 512 + hp * 128 + c8 * 8);
      *(uint4*)(&Vs[row * 128 + c8 * 8]) =
          *(const uint4*)(Vb + (size_t)(n0 + row) * 512 + hp * 128 + c8 * 8);
    }
    __syncthreads();
    for (int nn = 0; nn < 64; ++nn) {
      const uint2 kw0 = *(const uint2*)(&Ks[nn * 128 + tm * 4]);
      const uint2 kw1 = *(const uint2*)(&Ks[nn * 128 + 64 + tm * 4]);
      const uint2 vw0 = *(const uint2*)(&Vs[nn * 128 + td * 4]);
      const uint2 vw1 = *(const uint2*)(&Vs[nn * 128 + 64 + td * 4]);
      const float km0[4] = {bflo(kw0.x), bfhi(kw0.x), bflo(kw0.y), bfhi(kw0.y)};
      const float km1[4] = {bflo(kw1.x), bfhi(kw1.x), bflo(kw1.y), bfhi(kw1.y)};
      const float vd0[4] = {bflo(vw0.x), bfhi(vw0.x), bflo(vw0.y), bfhi(vw0.y)};
      const float vd1[4] = {bflo(vw1.x), bfhi(vw1.x), bflo(vw1.y), bfhi(vw1.y)};
#pragma unroll
      for (int a = 0; a < 4; ++a)
#pragma unroll
        for (int b = 0; b < 4; ++b) {
          acc0[a][b] = fmaf(km0[a], vd0[b], acc0[a][b]);
          acc1[a][b] = fmaf(km1[a], vd1[b], acc1[a][b]);
        }
    }
    __syncthreads();
  }
  const int h0 = hp * 2;
#pragma unroll
  for (int a = 0; a < 4; ++a)
#pragma unroll
    for (int b = 0; b < 4; ++b) {
      atomicAdd(&kvs[(size_t)(h0 * 64 + tm * 4 + a) * 64 + td * 4 + b], acc0[a][b]);
      atomicAdd(&kvs[(size_t)((h0 + 1) * 64 + tm * 4 + a) * 64 + td * 4 + b], acc1[a][b]);
    }
}

// ---------------------------------------------------------------------------
// K2b: kvsT[d][k] = bf16(kvs[k][d])   (k = h*64+m in 0..511, d in 0..63)
// ---------------------------------------------------------------------------
__global__ void k_kvsT(const float* __restrict__ kvs, uint16_t* __restrict__ kvsT) {
  const int t = blockIdx.x * 256 + threadIdx.x;
  const int e0 = t * 4;
  const float4 v = *(const float4*)(kvs + e0);
  const int k = e0 >> 6, d0 = e0 & 63;
  kvsT[(size_t)(d0 + 0) * 512 + k] = f2bf(v.x);
  kvsT[(size_t)(d0 + 1) * 512 + k] = f2bf(v.y);
  kvsT[(size_t)(d0 + 2) * 512 + k] = f2bf(v.z);
  kvsT[(size_t)(d0 + 3) * 512 + k] = f2bf(v.w);
}

// ---------------------------------------------------------------------------
// K3 (fused): den prologue -> aS,bS; out = (aQ)@kvsT^T + (bV)@I_blockdiag.
// ---------------------------------------------------------------------------
__global__ __launch_bounds__(256) void k_num(const uint16_t* __restrict__ Qb,
                                             const uint16_t* __restrict__ Vb,
                                             const uint16_t* __restrict__ kvsT,
                                             const float* __restrict__ ks_sum,
                                             const float* __restrict__ norms,
                                             float* __restrict__ out) {
  __shared__ float kss[512];
  __shared__ float aS[64 * 8];
  __shared__ float bS[64 * 8];
  const int tid = threadIdx.x, lane = tid & 63, wv = tid >> 6;
  const int l15 = lane & 15, lhi = lane >> 4;
  const int row0 = blockIdx.x * 64;

  kss[tid] = ks_sum[tid];
  kss[tid + 256] = ks_sum[tid + 256];
  __syncthreads();
  const float scale = 1.0f / (sqrtf(norms[0]) * sqrtf(norms[1]));

  {  // den: thread t -> row r = t>>2, heads (t&3)*2 and +1
    const int r = tid >> 2, h0 = (tid & 3) * 2;
#pragma unroll
    for (int hh = 0; hh < 2; ++hh) {
      const int h = h0 + hh;
      const uint16_t* q = Qb + (size_t)(row0 + r) * 512 + h * 64;
      const float* ks = &kss[h * 64];
      float dot = 0.f;
#pragma unroll
      for (int i = 0; i < 8; ++i) {
        const uint4 w = *(const uint4*)(q + i * 8);
        const uint32_t dw[4] = {w.x, w.y, w.z, w.w};
#pragma unroll
        for (int c = 0; c < 4; ++c) {
          dot = fmaf(bflo(dw[c]), ks[i * 8 + c * 2], dot);
          dot = fmaf(bfhi(dw[c]), ks[i * 8 + c * 2 + 1], dot);
        }
      }
      const float den = fmaf(scale, dot, 65536.0f);
      aS[r * 8 + h] = scale / (8.0f * den);
      bS[r * 8 + h] = 8192.0f / den;
    }
  }
  __syncthreads();

  // constant identity B-fragments: B[k][d] = (k%64 == d), k-slice (kk,lhi)
  short8 If[2][4];
#pragma unroll
  for (int kk = 0; kk < 2; ++kk)
#pragma unroll
    for (int n = 0; n < 4; ++n) {
      const int pos = n * 16 + l15 - kk * 32 - lhi * 8;  // hit if 0..7
      uint32_t* p = (uint32_t*)&If[kk][n];
#pragma unroll
      for (int jw = 0; jw < 4; ++jw)
        p[jw] = ((pos >> 1) == jw) ? ((pos & 1) ? 0x3F800000u : 0x00003F80u) : 0u;
    }

  const int myrow = row0 + wv * 16 + l15;
  f32x4 acc[4];
#pragma unroll
  for (int n = 0; n < 4; ++n) acc[n] = (f32x4){0.f, 0.f, 0.f, 0.f};

  // Phase 1: a-scaled Q against kvsT   (k = h*64 + kk*32 + lhi*8 + j)
  for (int h = 0; h < 8; ++h) {
    const float sc = aS[(wv * 16 + l15) * 8 + h];
#pragma unroll
    for (int kk = 0; kk < 2; ++kk) {
      const uint4 w = *(const uint4*)(Qb + (size_t)myrow * 512 + h * 64 + kk * 32 + lhi * 8);
      const uint32_t dw[4] = {w.x, w.y, w.z, w.w};
      short8 af;
      uint32_t* ap = (uint32_t*)&af;
#pragma unroll
      for (int c = 0; c < 4; ++c) ap[c] = pk2bf(bflo(dw[c]) * sc, bfhi(dw[c]) * sc);
#pragma unroll
      for (int n = 0; n < 4; ++n) {
        const short8 bf =
            *(const short8*)(kvsT + (size_t)(n * 16 + l15) * 512 + h * 64 + kk * 32 + lhi * 8);
        acc[n] = __builtin_amdgcn_mfma_f32_16x16x32_bf16(af, bf, acc[n], 0, 0, 0);
      }
    }
  }
  // Phase 2: b-scaled V against block-diag identity
  for (int h = 0; h < 8; ++h) {
    const float sc = bS[(wv * 16 + l15) * 8 + h];
#pragma unroll
    for (int kk = 0; kk < 2; ++kk) {
      const uint4 w = *(const uint4*)(Vb + (size_t)myrow * 512 + h * 64 + kk * 32 + lhi * 8);
      const uint32_t dw[4] = {w.x, w.y, w.z, w.w};
      short8 af;
      uint32_t* ap = (uint32_t*)&af;
#pragma unroll
      for (int c = 0; c < 4; ++c) ap[c] = pk2bf(bflo(dw[c]) * sc, bfhi(dw[c]) * sc);
#pragma unroll
      for (int n = 0; n < 4; ++n)
        acc[n] = __builtin_amdgcn_mfma_f32_16x16x32_bf16(af, If[kk][n], acc[n], 0, 0, 0);
    }
  }

#pragma unroll
  for (int n = 0; n < 4; ++n)
#pragma unroll
    for (int j = 0; j < 4; ++j)
      out[(size_t)(row0 + wv * 16 + lhi * 4 + j) * 64 + n * 16 + l15] = acc[n][j];
}

// ---------------------------------------------------------------------------
extern "C" void kernel_launch(void* const* d_in, const int* in_sizes, int n_in,
                              void* d_out, int out_size, void* d_ws, size_t ws_size,
                              hipStream_t stream) {
  const float* qin = (const float*)d_in[0];
  const float* sin_ = (const float*)d_in[1];
  const float* Wq = (const float*)d_in[2];
  const float* bq = (const float*)d_in[3];
  const float* Wk = (const float*)d_in[4];
  const float* bk = (const float*)d_in[5];
  const float* Wv = (const float*)d_in[6];
  const float* bv = (const float*)d_in[7];
  float* out = (float*)d_out;

  char* ws = (char*)d_ws;
  float* kvs = (float*)ws;                          // 128KB
  float* ks_sum = (float*)(ws + 131072);            // 2KB
  float* norms = (float*)(ws + 133120);             // 8B
  uint16_t* kvsT = (uint16_t*)(ws + 262144);        // 64KB
  uint16_t* Wb = (uint16_t*)(ws + 393216);          // 1.5MB
  uint16_t* Qb = (uint16_t*)(ws + (2ull << 20));                     // 64MB
  uint16_t* Kb = (uint16_t*)(ws + (2ull << 20) + 67108864ull);       // 64MB
  uint16_t* Vb = (uint16_t*)(ws + (2ull << 20) + 134217728ull);      // 64MB

  hipMemsetAsync(d_ws, 0, 133128, stream);  // kvs, ks_sum, norms

  k_cvtw<<<dim3(768), dim3(256), 0, stream>>>(Wq, Wk, Wv, Wb);
  k_gemm_qkv<<<dim3(6144), dim3(256), 0, stream>>>(qin, sin_, Wb, bq, bk, bv,
                                                   Qb, Kb, Vb, norms, ks_sum);
  k_kvs<<<dim3(1024), dim3(256), 0, stream>>>(Kb, Vb, kvs);
  k_kvsT<<<dim3(32), dim3(256), 0, stream>>>(kvs, kvsT);
  k_num<<<dim3(1024), dim3(256), 0, stream>>>(Qb, Vb, kvsT, ks_sum, norms, out);
}